// Round 5
// baseline (440.432 us; speedup 1.0000x reference)
//
#include <hip/hip_runtime.h>
#include <math.h>

#define N_NODES 50000
#define SLAB 800000   // 50000 nodes * 16 floats: one feature-block slab

typedef float f32x4 __attribute__((ext_vector_type(4)));

// ---------------------------------------------------------------------------
// int32 vs int64 edge_index layout probe (odd words all-zero <=> int64).
// ---------------------------------------------------------------------------
__global__ void detect_idx(const int* __restrict__ idx, int* __restrict__ flag) {
    if (blockIdx.x == 0 && threadIdx.x == 0) {
        int nz = 0;
#pragma unroll
        for (int i = 0; i < 32; ++i) nz += (idx[2 * i + 1] != 0) ? 1 : 0;
        flag[0] = (nz == 0) ? 2 : 1;  // element stride in 32-bit words
    }
}

__global__ void count_edges(const int* __restrict__ idx, const int* __restrict__ flag,
                            int E, int* __restrict__ cnt) {
    int st = flag[0];
    int e = blockIdx.x * blockDim.x + threadIdx.x;
    if (e < E) {
        int d = idx[(size_t)(E + e) * st];
        atomicAdd(&cnt[d], 1);
    }
}

// ---------------------------------------------------------------------------
// Parallel exclusive scan (3 small kernels). S1 fuses dinv = rsqrt(deg+1).
// ---------------------------------------------------------------------------
__global__ __launch_bounds__(1024) void scan_reduce_dinv(const int* __restrict__ cnt,
                                                         float* __restrict__ dinv,
                                                         int* __restrict__ bsum, int n) {
    __shared__ int wsum[16];
    int tid = threadIdx.x, lane = tid & 63, wid = tid >> 6;
    int i0 = blockIdx.x * 4096 + tid * 4;
    int s = 0;
#pragma unroll
    for (int i = 0; i < 4; ++i) {
        if (i0 + i < n) {
            int c = cnt[i0 + i];
            s += c;
            dinv[i0 + i] = rsqrtf((float)(c + 1));
        }
    }
#pragma unroll
    for (int o = 1; o < 64; o <<= 1) s += __shfl_xor(s, o, 64);
    if (lane == 0) wsum[wid] = s;
    __syncthreads();
    if (tid == 0) {
        int t = 0;
#pragma unroll
        for (int w = 0; w < 16; ++w) t += wsum[w];
        bsum[blockIdx.x] = t;
    }
}

__global__ void scan_partials(int* __restrict__ bsum, int* __restrict__ offs,
                              int nb, int n) {
    int lane = threadIdx.x;
    int orig = (lane < nb) ? bsum[lane] : 0;
    int v = orig;
#pragma unroll
    for (int o = 1; o < 64; o <<= 1) {
        int t = __shfl_up(v, o, 64);
        if (lane >= o) v += t;
    }
    if (lane < nb) bsum[lane] = v - orig;   // exclusive
    if (lane == nb - 1) offs[n] = v;        // total
}

__global__ __launch_bounds__(1024) void scan_block(const int* __restrict__ cnt,
                                                   const int* __restrict__ bsum,
                                                   int* __restrict__ offs,
                                                   int* __restrict__ cursor, int n) {
    __shared__ int wsum[16];
    int tid = threadIdx.x, lane = tid & 63, wid = tid >> 6;
    int i0 = blockIdx.x * 4096 + tid * 4;
    int v0 = (i0 + 0 < n) ? cnt[i0 + 0] : 0;
    int v1 = (i0 + 1 < n) ? cnt[i0 + 1] : 0;
    int v2 = (i0 + 2 < n) ? cnt[i0 + 2] : 0;
    int v3 = (i0 + 3 < n) ? cnt[i0 + 3] : 0;
    int tot = v0 + v1 + v2 + v3;
    int sc = tot;
#pragma unroll
    for (int o = 1; o < 64; o <<= 1) {
        int t = __shfl_up(sc, o, 64);
        if (lane >= o) sc += t;
    }
    if (lane == 63) wsum[wid] = sc;
    __syncthreads();
    int wpre = 0;
    for (int w = 0; w < wid; ++w) wpre += wsum[w];
    int run = bsum[blockIdx.x] + wpre + (sc - tot);
    if (i0 + 0 < n) { offs[i0 + 0] = run; cursor[i0 + 0] = run; } run += v0;
    if (i0 + 1 < n) { offs[i0 + 1] = run; cursor[i0 + 1] = run; } run += v1;
    if (i0 + 2 < n) { offs[i0 + 2] = run; cursor[i0 + 2] = run; } run += v2;
    if (i0 + 3 < n) { offs[i0 + 3] = run; cursor[i0 + 3] = run; }
}

__global__ void scatter_edges(const int* __restrict__ idx, const int* __restrict__ flag,
                              int E, int* __restrict__ cursor, int* __restrict__ csrc) {
    int st = flag[0];
    int e = blockIdx.x * blockDim.x + threadIdx.x;
    if (e < E) {
        int s = idx[(size_t)e * st];
        int d = idx[(size_t)(E + e) * st];
        int p = atomicAdd(&cursor[d], 1);
        csrc[p] = s;
    }
}

// ---------------------------------------------------------------------------
// GEMM1: h1b[fb][node][16] = x[M x 128] * W1[128 x 128], blocked epilogue.
// ---------------------------------------------------------------------------
__global__ __launch_bounds__(256) void gemm_128(const float* __restrict__ A,
                                                const float* __restrict__ B,
                                                float* __restrict__ h1b, int M) {
    __shared__ float As[128 * 68];   // [k][r] transposed, 34.8 KB
    __shared__ float Bs[64 * 128];   // 32.8 KB
    int tid = threadIdx.x;
    int m0 = blockIdx.x * 64;
    int cg = tid & 15;   // cols cg*8 .. +7
    int rg = tid >> 4;   // rows rg*4 .. +3

#pragma unroll
    for (int it = 0; it < 8; ++it) {
        int lin = (it * 256 + tid) * 4;   // 0..8191
        int r = lin >> 7;
        int k = lin & 127;
        int row = m0 + r;
        float4 v = make_float4(0.f, 0.f, 0.f, 0.f);
        if (row < M) v = *(const float4*)&A[(size_t)row * 128 + k];
        As[(k + 0) * 68 + r] = v.x;
        As[(k + 1) * 68 + r] = v.y;
        As[(k + 2) * 68 + r] = v.z;
        As[(k + 3) * 68 + r] = v.w;
    }

    float acc[4][8];
#pragma unroll
    for (int j = 0; j < 4; ++j)
#pragma unroll
        for (int i = 0; i < 8; ++i) acc[j][i] = 0.f;

    for (int kb = 0; kb < 2; ++kb) {
        __syncthreads();
#pragma unroll
        for (int it = 0; it < 8; ++it) {
            int lin = (it * 256 + tid) * 4;  // 0..8191
            *(float4*)&Bs[lin] = *(const float4*)&B[kb * 8192 + lin];
        }
        __syncthreads();
#pragma unroll 2
        for (int k2 = 0; k2 < 64; ++k2) {
            float4 a  = *(const float4*)&As[(kb * 64 + k2) * 68 + rg * 4];
            float4 b0 = *(const float4*)&Bs[k2 * 128 + cg * 8];
            float4 b1 = *(const float4*)&Bs[k2 * 128 + cg * 8 + 4];
            float av[4] = {a.x, a.y, a.z, a.w};
#pragma unroll
            for (int j = 0; j < 4; ++j) {
                acc[j][0] += av[j] * b0.x; acc[j][1] += av[j] * b0.y;
                acc[j][2] += av[j] * b0.z; acc[j][3] += av[j] * b0.w;
                acc[j][4] += av[j] * b1.x; acc[j][5] += av[j] * b1.y;
                acc[j][6] += av[j] * b1.z; acc[j][7] += av[j] * b1.w;
            }
        }
    }

    // blocked write: cols cg*8..+7 live in feature-block fb = cg>>1
    int fb = cg >> 1;
    int off = (cg & 1) * 8;
#pragma unroll
    for (int j = 0; j < 4; ++j) {
        int row = m0 + rg * 4 + j;
        if (row < M) {
            float* dst = &h1b[(size_t)fb * SLAB + (size_t)row * 16 + off];
            *(float4*)&dst[0] = make_float4(acc[j][0], acc[j][1], acc[j][2], acc[j][3]);
            *(float4*)&dst[4] = make_float4(acc[j][4], acc[j][5], acc[j][6], acc[j][7]);
        }
    }
}

// GEMM2: h2b[fb][node][16] = h1r[M x 128] * W2[128 x 64], blocked epilogue.
__global__ __launch_bounds__(256) void gemm_64(const float* __restrict__ A,
                                               const float* __restrict__ B,
                                               float* __restrict__ h2b, int M) {
    __shared__ float As[128 * 68];
    __shared__ float Bs[128 * 64];
    int tid = threadIdx.x;
    int m0 = blockIdx.x * 64;
    int cg = tid & 15;   // cols cg*4 .. +3
    int rg = tid >> 4;   // rows rg*4 .. +3

#pragma unroll
    for (int it = 0; it < 8; ++it) {
        int lin = (it * 256 + tid) * 4;
        int r = lin >> 7;
        int k = lin & 127;
        int row = m0 + r;
        float4 v = make_float4(0.f, 0.f, 0.f, 0.f);
        if (row < M) v = *(const float4*)&A[(size_t)row * 128 + k];
        As[(k + 0) * 68 + r] = v.x;
        As[(k + 1) * 68 + r] = v.y;
        As[(k + 2) * 68 + r] = v.z;
        As[(k + 3) * 68 + r] = v.w;
    }
#pragma unroll
    for (int it = 0; it < 8; ++it) {
        int lin = (it * 256 + tid) * 4;  // 0..8191
        *(float4*)&Bs[lin] = *(const float4*)&B[lin];
    }
    __syncthreads();

    float acc[4][4];
#pragma unroll
    for (int j = 0; j < 4; ++j)
#pragma unroll
        for (int i = 0; i < 4; ++i) acc[j][i] = 0.f;

#pragma unroll 2
    for (int k = 0; k < 128; ++k) {
        float4 a = *(const float4*)&As[k * 68 + rg * 4];
        float4 b = *(const float4*)&Bs[k * 64 + cg * 4];
        float av[4] = {a.x, a.y, a.z, a.w};
#pragma unroll
        for (int j = 0; j < 4; ++j) {
            acc[j][0] += av[j] * b.x; acc[j][1] += av[j] * b.y;
            acc[j][2] += av[j] * b.z; acc[j][3] += av[j] * b.w;
        }
    }

    int fb = cg >> 2;
    int off = (cg & 3) * 4;
#pragma unroll
    for (int j = 0; j < 4; ++j) {
        int row = m0 + rg * 4 + j;
        if (row < M) {
            *(float4*)&h2b[(size_t)fb * SLAB + (size_t)row * 16 + off] =
                make_float4(acc[j][0], acc[j][1], acc[j][2], acc[j][3]);
        }
    }
}

// ---------------------------------------------------------------------------
// Aggregation layer 1, one WAVE per (node, feature-block).
// fb = blockIdx%8 -> XCD pin (slab L2-resident, proven by R4 FETCH collapse).
// Wave shape: 16 edge-slots x 4 feature-lanes -> 16 independent 64B gathers
// in flight, wave-uniform loop (no divergence); butterfly-reduce slots.
// ---------------------------------------------------------------------------
__global__ __launch_bounds__(256) void aggregate_relu_fb(
    const float* __restrict__ h1b, const int* __restrict__ offs,
    const int* __restrict__ csrc, const float* __restrict__ dinv,
    const float* __restrict__ bias, float* __restrict__ h1r) {
    int fb = blockIdx.x & 7;
    int tile = blockIdx.x >> 3;
    int tid = threadIdx.x;
    int wave = tid >> 6;
    int lane = tid & 63;
    int grp = lane >> 2;   // edge slot 0..15
    int sub = lane & 3;    // float4 slice of the 16-float slab row
    int g = tile * 4 + wave;
    if (g >= N_NODES) return;
    const f32x4* slab = (const f32x4*)(h1b + (size_t)fb * SLAB);
    float di = dinv[g];
    int e0 = offs[g], e1 = offs[g + 1];
    f32x4 acc = {0.f, 0.f, 0.f, 0.f};
    int nb = (e1 - e0 + 15) >> 4;
    for (int it = 0; it < nb; ++it) {
        int e = e0 + it * 16 + grp;
        bool ok = e < e1;
        int s = ok ? csrc[e] : 0;
        float w = ok ? dinv[s] * di : 0.f;
        f32x4 v = slab[(size_t)s * 4 + sub];
        acc += w * v;
    }
#pragma unroll
    for (int o = 4; o < 64; o <<= 1) {
        acc.x += __shfl_xor(acc.x, o, 64);
        acc.y += __shfl_xor(acc.y, o, 64);
        acc.z += __shfl_xor(acc.z, o, 64);
        acc.w += __shfl_xor(acc.w, o, 64);
    }
    if (lane < 4) {
        float sw = di * di;
        f32x4 self = slab[(size_t)g * 4 + lane];
        f32x4 b = ((const f32x4*)bias)[fb * 4 + lane];
        f32x4 o4 = acc + sw * self + b;
        o4.x = fmaxf(o4.x, 0.f); o4.y = fmaxf(o4.y, 0.f);
        o4.z = fmaxf(o4.z, 0.f); o4.w = fmaxf(o4.w, 0.f);
        *(f32x4*)&h1r[(size_t)g * 128 + fb * 16 + lane * 4] = o4;
    }
}

// Aggregation layer 2: wave per (node, fb), 4 fbs x 2 node-halves -> 8 slots.
__global__ __launch_bounds__(256) void aggregate_fb_64(
    const float* __restrict__ h2b, const int* __restrict__ offs,
    const int* __restrict__ csrc, const float* __restrict__ dinv,
    const float* __restrict__ bias, float* __restrict__ h3) {
    int slot = blockIdx.x & 7;
    int fb = slot & 3;
    int half = slot >> 2;
    int tile = blockIdx.x >> 3;   // 0..6249
    int tid = threadIdx.x;
    int wave = tid >> 6;
    int lane = tid & 63;
    int grp = lane >> 2;
    int sub = lane & 3;
    int g = (half * 6250 + tile) * 4 + wave;
    if (g >= N_NODES) return;
    const f32x4* slab = (const f32x4*)(h2b + (size_t)fb * SLAB);
    float di = dinv[g];
    int e0 = offs[g], e1 = offs[g + 1];
    f32x4 acc = {0.f, 0.f, 0.f, 0.f};
    int nb = (e1 - e0 + 15) >> 4;
    for (int it = 0; it < nb; ++it) {
        int e = e0 + it * 16 + grp;
        bool ok = e < e1;
        int s = ok ? csrc[e] : 0;
        float w = ok ? dinv[s] * di : 0.f;
        f32x4 v = slab[(size_t)s * 4 + sub];
        acc += w * v;
    }
#pragma unroll
    for (int o = 4; o < 64; o <<= 1) {
        acc.x += __shfl_xor(acc.x, o, 64);
        acc.y += __shfl_xor(acc.y, o, 64);
        acc.z += __shfl_xor(acc.z, o, 64);
        acc.w += __shfl_xor(acc.w, o, 64);
    }
    if (lane < 4) {
        float sw = di * di;
        f32x4 self = slab[(size_t)g * 4 + lane];
        f32x4 b = ((const f32x4*)bias)[fb * 4 + lane];
        f32x4 o4 = acc + sw * self + b;
        *(f32x4*)&h3[(size_t)g * 64 + fb * 16 + lane * 4] = o4;
    }
}

// Streaming softmax over 64 logits/node: 16 lanes/node, in-register.
__global__ __launch_bounds__(256) void softmax_64(const float* __restrict__ h3,
                                                  float* __restrict__ out) {
    int tid = threadIdx.x;
    int g = blockIdx.x * 16 + (tid >> 4);
    int lane = tid & 15;
    if (g >= N_NODES) return;
    float4 acc = ((const float4*)h3)[(size_t)g * 16 + lane];
    float m = fmaxf(fmaxf(acc.x, acc.y), fmaxf(acc.z, acc.w));
#pragma unroll
    for (int o = 1; o < 16; o <<= 1) m = fmaxf(m, __shfl_xor(m, o, 64));
    float4 e4;
    e4.x = expf(acc.x - m); e4.y = expf(acc.y - m);
    e4.z = expf(acc.z - m); e4.w = expf(acc.w - m);
    float s = e4.x + e4.y + e4.z + e4.w;
#pragma unroll
    for (int o = 1; o < 16; o <<= 1) s += __shfl_xor(s, o, 64);
    float inv = 1.0f / s;
    e4.x *= inv; e4.y *= inv; e4.z *= inv; e4.w *= inv;
    ((float4*)out)[(size_t)g * 16 + lane] = e4;
}

extern "C" void kernel_launch(void* const* d_in, const int* in_sizes, int n_in,
                              void* d_out, int out_size, void* d_ws, size_t ws_size,
                              hipStream_t stream) {
    const float* x  = (const float*)d_in[0];
    const int*   idx = (const int*)d_in[1];
    const float* W1 = (const float*)d_in[2];
    const float* b1 = (const float*)d_in[3];
    const float* W2 = (const float*)d_in[4];
    const float* b2 = (const float*)d_in[5];
    float* outp = (float*)d_out;
    int E = in_sizes[1] / 2;
    int nscan = (N_NODES + 4095) / 4096;  // 13

    char* ws = (char*)d_ws;
    size_t off = 0;
    auto alloc = [&](size_t bytes) {
        size_t o = off;
        off += (bytes + 255) & ~(size_t)255;
        return o;
    };
    // Region A (25.6 MB): h1b (gemm1 out / agg1 in); reused after agg1:
    // lower half = h2b (gemm2 out), upper half = h3 logits.
    float* regA = (float*)(ws + alloc((size_t)8 * SLAB * 4));
    float* h1b  = regA;
    float* h2b  = regA;                     // 4 slabs = 12.8 MB
    float* h3   = regA + (size_t)4 * SLAB;  // 12.8 MB
    float* h1r  = (float*)(ws + alloc((size_t)N_NODES * 128 * 4));
    int*   csrc = (int*)  (ws + alloc((size_t)E * 4));
    int*   cnt  = (int*)  (ws + alloc((size_t)N_NODES * 4));
    int*   offs = (int*)  (ws + alloc((size_t)(N_NODES + 1) * 4));
    int*   cursor = (int*)(ws + alloc((size_t)N_NODES * 4));
    float* dinv = (float*)(ws + alloc((size_t)N_NODES * 4));
    int*   bsum = (int*)  (ws + alloc((size_t)nscan * 4));
    int*   flag = (int*)  (ws + alloc(256));

    hipMemsetAsync(cnt, 0, (size_t)N_NODES * 4, stream);
    detect_idx<<<1, 64, 0, stream>>>(idx, flag);
    count_edges<<<(E + 255) / 256, 256, 0, stream>>>(idx, flag, E, cnt);
    scan_reduce_dinv<<<nscan, 1024, 0, stream>>>(cnt, dinv, bsum, N_NODES);
    scan_partials<<<1, 64, 0, stream>>>(bsum, offs, nscan, N_NODES);
    scan_block<<<nscan, 1024, 0, stream>>>(cnt, bsum, offs, cursor, N_NODES);
    scatter_edges<<<(E + 255) / 256, 256, 0, stream>>>(idx, flag, E, cursor, csrc);
    gemm_128<<<(N_NODES + 63) / 64, 256, 0, stream>>>(x, W1, h1b, N_NODES);
    aggregate_relu_fb<<<8 * ((N_NODES + 3) / 4), 256, 0, stream>>>(h1b, offs, csrc, dinv, b1, h1r);
    gemm_64<<<(N_NODES + 63) / 64, 256, 0, stream>>>(h1r, W2, h2b, N_NODES);
    aggregate_fb_64<<<8 * 6250, 256, 0, stream>>>(h2b, offs, csrc, dinv, b2, h3);
    softmax_64<<<(N_NODES + 15) / 16, 256, 0, stream>>>(h3, outp);
}

// Round 8
// 379.515 us; speedup vs baseline: 1.1605x; 1.1605x over previous
//
#include <hip/hip_runtime.h>
#include <math.h>

#define N_NODES 50000
#define SLAB 800000   // 50000 nodes * 16 floats: one feature-block slab

typedef float f32x4 __attribute__((ext_vector_type(4)));

// ---------------------------------------------------------------------------
// int32 vs int64 edge_index layout probe (odd words all-zero <=> int64).
// ---------------------------------------------------------------------------
__global__ void detect_idx(const int* __restrict__ idx, int* __restrict__ flag) {
    if (blockIdx.x == 0 && threadIdx.x == 0) {
        int nz = 0;
#pragma unroll
        for (int i = 0; i < 32; ++i) nz += (idx[2 * i + 1] != 0) ? 1 : 0;
        flag[0] = (nz == 0) ? 2 : 1;  // element stride in 32-bit words
    }
}

__global__ void count_edges(const int* __restrict__ idx, const int* __restrict__ flag,
                            int E, int* __restrict__ cnt) {
    int st = flag[0];
    int e = blockIdx.x * blockDim.x + threadIdx.x;
    if (e < E) {
        int d = idx[(size_t)(E + e) * st];
        atomicAdd(&cnt[d], 1);
    }
}

// ---------------------------------------------------------------------------
// Parallel exclusive scan (3 small kernels). S1 fuses dinv = rsqrt(deg+1).
// ---------------------------------------------------------------------------
__global__ __launch_bounds__(1024) void scan_reduce_dinv(const int* __restrict__ cnt,
                                                         float* __restrict__ dinv,
                                                         int* __restrict__ bsum, int n) {
    __shared__ int wsum[16];
    int tid = threadIdx.x, lane = tid & 63, wid = tid >> 6;
    int i0 = blockIdx.x * 4096 + tid * 4;
    int s = 0;
#pragma unroll
    for (int i = 0; i < 4; ++i) {
        if (i0 + i < n) {
            int c = cnt[i0 + i];
            s += c;
            dinv[i0 + i] = rsqrtf((float)(c + 1));
        }
    }
#pragma unroll
    for (int o = 1; o < 64; o <<= 1) s += __shfl_xor(s, o, 64);
    if (lane == 0) wsum[wid] = s;
    __syncthreads();
    if (tid == 0) {
        int t = 0;
#pragma unroll
        for (int w = 0; w < 16; ++w) t += wsum[w];
        bsum[blockIdx.x] = t;
    }
}

__global__ void scan_partials(int* __restrict__ bsum, int* __restrict__ offs,
                              int nb, int n) {
    int lane = threadIdx.x;
    int orig = (lane < nb) ? bsum[lane] : 0;
    int v = orig;
#pragma unroll
    for (int o = 1; o < 64; o <<= 1) {
        int t = __shfl_up(v, o, 64);
        if (lane >= o) v += t;
    }
    if (lane < nb) bsum[lane] = v - orig;   // exclusive
    if (lane == nb - 1) offs[n] = v;        // total
}

__global__ __launch_bounds__(1024) void scan_block(const int* __restrict__ cnt,
                                                   const int* __restrict__ bsum,
                                                   int* __restrict__ offs,
                                                   int* __restrict__ cursor, int n) {
    __shared__ int wsum[16];
    int tid = threadIdx.x, lane = tid & 63, wid = tid >> 6;
    int i0 = blockIdx.x * 4096 + tid * 4;
    int v0 = (i0 + 0 < n) ? cnt[i0 + 0] : 0;
    int v1 = (i0 + 1 < n) ? cnt[i0 + 1] : 0;
    int v2 = (i0 + 2 < n) ? cnt[i0 + 2] : 0;
    int v3 = (i0 + 3 < n) ? cnt[i0 + 3] : 0;
    int tot = v0 + v1 + v2 + v3;
    int sc = tot;
#pragma unroll
    for (int o = 1; o < 64; o <<= 1) {
        int t = __shfl_up(sc, o, 64);
        if (lane >= o) sc += t;
    }
    if (lane == 63) wsum[wid] = sc;
    __syncthreads();
    int wpre = 0;
    for (int w = 0; w < wid; ++w) wpre += wsum[w];
    int run = bsum[blockIdx.x] + wpre + (sc - tot);
    if (i0 + 0 < n) { offs[i0 + 0] = run; cursor[i0 + 0] = run; } run += v0;
    if (i0 + 1 < n) { offs[i0 + 1] = run; cursor[i0 + 1] = run; } run += v1;
    if (i0 + 2 < n) { offs[i0 + 2] = run; cursor[i0 + 2] = run; } run += v2;
    if (i0 + 3 < n) { offs[i0 + 3] = run; cursor[i0 + 3] = run; }
}

// Scatter packed (src | dst_local<<16): src < 2^16, dst_local = d & 127
// (CSR tiles are 128-aligned so d&127 == d - tile_base).
__global__ void scatter_edges(const int* __restrict__ idx, const int* __restrict__ flag,
                              int E, int* __restrict__ cursor, int* __restrict__ pkd) {
    int st = flag[0];
    int e = blockIdx.x * blockDim.x + threadIdx.x;
    if (e < E) {
        int s = idx[(size_t)e * st];
        int d = idx[(size_t)(E + e) * st];
        int p = atomicAdd(&cursor[d], 1);
        pkd[p] = s | ((d & 127) << 16);
    }
}

// ---------------------------------------------------------------------------
// GEMM1: h1s[fb][node][16] = dinv[node] * (x[M x 128] * W1)[node], blocked.
// ---------------------------------------------------------------------------
__global__ __launch_bounds__(256) void gemm_128(const float* __restrict__ A,
                                                const float* __restrict__ B,
                                                const float* __restrict__ dinv,
                                                float* __restrict__ h1s, int M) {
    __shared__ float As[128 * 68];   // [k][r] transposed, 34.8 KB
    __shared__ float Bs[64 * 128];   // 32.8 KB
    int tid = threadIdx.x;
    int m0 = blockIdx.x * 64;
    int cg = tid & 15;   // cols cg*8 .. +7
    int rg = tid >> 4;   // rows rg*4 .. +3

#pragma unroll
    for (int it = 0; it < 8; ++it) {
        int lin = (it * 256 + tid) * 4;   // 0..8191
        int r = lin >> 7;
        int k = lin & 127;
        int row = m0 + r;
        float4 v = make_float4(0.f, 0.f, 0.f, 0.f);
        if (row < M) v = *(const float4*)&A[(size_t)row * 128 + k];
        As[(k + 0) * 68 + r] = v.x;
        As[(k + 1) * 68 + r] = v.y;
        As[(k + 2) * 68 + r] = v.z;
        As[(k + 3) * 68 + r] = v.w;
    }

    float acc[4][8];
#pragma unroll
    for (int j = 0; j < 4; ++j)
#pragma unroll
        for (int i = 0; i < 8; ++i) acc[j][i] = 0.f;

    for (int kb = 0; kb < 2; ++kb) {
        __syncthreads();
#pragma unroll
        for (int it = 0; it < 8; ++it) {
            int lin = (it * 256 + tid) * 4;  // 0..8191
            *(float4*)&Bs[lin] = *(const float4*)&B[kb * 8192 + lin];
        }
        __syncthreads();
#pragma unroll 2
        for (int k2 = 0; k2 < 64; ++k2) {
            float4 a  = *(const float4*)&As[(kb * 64 + k2) * 68 + rg * 4];
            float4 b0 = *(const float4*)&Bs[k2 * 128 + cg * 8];
            float4 b1 = *(const float4*)&Bs[k2 * 128 + cg * 8 + 4];
            float av[4] = {a.x, a.y, a.z, a.w};
#pragma unroll
            for (int j = 0; j < 4; ++j) {
                acc[j][0] += av[j] * b0.x; acc[j][1] += av[j] * b0.y;
                acc[j][2] += av[j] * b0.z; acc[j][3] += av[j] * b0.w;
                acc[j][4] += av[j] * b1.x; acc[j][5] += av[j] * b1.y;
                acc[j][6] += av[j] * b1.z; acc[j][7] += av[j] * b1.w;
            }
        }
    }

    int fb = cg >> 1;
    int off = (cg & 1) * 8;
#pragma unroll
    for (int j = 0; j < 4; ++j) {
        int row = m0 + rg * 4 + j;
        if (row < M) {
            float di = dinv[row];
            float* dst = &h1s[(size_t)fb * SLAB + (size_t)row * 16 + off];
            *(float4*)&dst[0] = make_float4(di * acc[j][0], di * acc[j][1],
                                            di * acc[j][2], di * acc[j][3]);
            *(float4*)&dst[4] = make_float4(di * acc[j][4], di * acc[j][5],
                                            di * acc[j][6], di * acc[j][7]);
        }
    }
}

// GEMM2: h2s[fb][node][16] = dinv[node] * (h1r[M x 128] * W2)[node], blocked.
__global__ __launch_bounds__(256) void gemm_64(const float* __restrict__ A,
                                               const float* __restrict__ B,
                                               const float* __restrict__ dinv,
                                               float* __restrict__ h2s, int M) {
    __shared__ float As[128 * 68];
    __shared__ float Bs[128 * 64];
    int tid = threadIdx.x;
    int m0 = blockIdx.x * 64;
    int cg = tid & 15;   // cols cg*4 .. +3
    int rg = tid >> 4;   // rows rg*4 .. +3

#pragma unroll
    for (int it = 0; it < 8; ++it) {
        int lin = (it * 256 + tid) * 4;
        int r = lin >> 7;
        int k = lin & 127;
        int row = m0 + r;
        float4 v = make_float4(0.f, 0.f, 0.f, 0.f);
        if (row < M) v = *(const float4*)&A[(size_t)row * 128 + k];
        As[(k + 0) * 68 + r] = v.x;
        As[(k + 1) * 68 + r] = v.y;
        As[(k + 2) * 68 + r] = v.z;
        As[(k + 3) * 68 + r] = v.w;
    }
#pragma unroll
    for (int it = 0; it < 8; ++it) {
        int lin = (it * 256 + tid) * 4;  // 0..8191
        *(float4*)&Bs[lin] = *(const float4*)&B[lin];
    }
    __syncthreads();

    float acc[4][4];
#pragma unroll
    for (int j = 0; j < 4; ++j)
#pragma unroll
        for (int i = 0; i < 4; ++i) acc[j][i] = 0.f;

#pragma unroll 2
    for (int k = 0; k < 128; ++k) {
        float4 a = *(const float4*)&As[k * 68 + rg * 4];
        float4 b = *(const float4*)&Bs[k * 64 + cg * 4];
        float av[4] = {a.x, a.y, a.z, a.w};
#pragma unroll
        for (int j = 0; j < 4; ++j) {
            acc[j][0] += av[j] * b.x; acc[j][1] += av[j] * b.y;
            acc[j][2] += av[j] * b.z; acc[j][3] += av[j] * b.w;
        }
    }

    int fb = cg >> 2;
    int off = (cg & 3) * 4;
#pragma unroll
    for (int j = 0; j < 4; ++j) {
        int row = m0 + rg * 4 + j;
        if (row < M) {
            float di = dinv[row];
            *(float4*)&h2s[(size_t)fb * SLAB + (size_t)row * 16 + off] =
                make_float4(di * acc[j][0], di * acc[j][1],
                            di * acc[j][2], di * acc[j][3]);
        }
    }
}

// ---------------------------------------------------------------------------
// Aggregation layer 1. Block = (fb, 128-node tile); fb = blockIdx%8 -> XCD
// pin (slab L2-resident, proven R4/R5 FETCH collapse). Flat contiguous edge
// stream: 64 quad-slots each own a contiguous ~EC/64 chunk. Same-dst runs
// accumulate in registers, flush to LDS (atomicAdd) on run boundaries.
// Weights pre-folded: slab holds dinv[s]*h1[s]; epilogue scales by dinv[d].
// ---------------------------------------------------------------------------
__global__ __launch_bounds__(256) void aggregate_relu_fb(
    const float* __restrict__ h1s, const int* __restrict__ offs,
    const int* __restrict__ pkd, const float* __restrict__ dinv,
    const float* __restrict__ bias, float* __restrict__ h1r) {
    __shared__ float acc[128 * 16];   // 8 KB
    int fb = blockIdx.x & 7;
    int tile = blockIdx.x >> 3;
    int n0 = tile * 128;
    int tid = threadIdx.x;
#pragma unroll
    for (int i = tid; i < 2048; i += 256) acc[i] = 0.f;
    __syncthreads();

    const f32x4* slab = (const f32x4*)(h1s + (size_t)fb * SLAB);
    int nEnd = min(n0 + 128, N_NODES);
    int E0 = offs[n0], E1 = offs[nEnd];
    int EC = E1 - E0;
    int slot = tid >> 2;
    int sub = tid & 3;
    int nit = (EC + 63) >> 6;
    int sBeg = slot * nit;
    int sEnd = min(sBeg + nit, EC);

    f32x4 racc = {0.f, 0.f, 0.f, 0.f};
    int cur = -1;
    for (int eo = sBeg; eo < sEnd; ++eo) {
        int pk = pkd[E0 + eo];
        int s = pk & 0xffff;
        int dl = pk >> 16;
        f32x4 v = slab[(size_t)s * 4 + sub];
        if (dl != cur) {
            if (cur >= 0) {
                atomicAdd(&acc[cur * 16 + sub * 4 + 0], racc.x);
                atomicAdd(&acc[cur * 16 + sub * 4 + 1], racc.y);
                atomicAdd(&acc[cur * 16 + sub * 4 + 2], racc.z);
                atomicAdd(&acc[cur * 16 + sub * 4 + 3], racc.w);
            }
            racc = v;
            cur = dl;
        } else {
            racc += v;
        }
    }
    if (cur >= 0) {
        atomicAdd(&acc[cur * 16 + sub * 4 + 0], racc.x);
        atomicAdd(&acc[cur * 16 + sub * 4 + 1], racc.y);
        atomicAdd(&acc[cur * 16 + sub * 4 + 2], racc.z);
        atomicAdd(&acc[cur * 16 + sub * 4 + 3], racc.w);
    }
    __syncthreads();

    // epilogue: thread t -> node t>>1, floats (t&1)*8 .. +7
    int ln = tid >> 1;
    int g = n0 + ln;
    if (g < N_NODES) {
        int c0 = (tid & 1) * 8;
        float di = dinv[g];
        f32x4 a0 = *(f32x4*)&acc[ln * 16 + c0];
        f32x4 a1 = *(f32x4*)&acc[ln * 16 + c0 + 4];
        f32x4 s0 = slab[(size_t)g * 4 + (c0 >> 2)];
        f32x4 s1 = slab[(size_t)g * 4 + (c0 >> 2) + 1];
        const f32x4* bv = (const f32x4*)&bias[fb * 16 + c0];
        f32x4 o0 = di * (a0 + s0) + bv[0];
        f32x4 o1 = di * (a1 + s1) + bv[1];
        o0.x = fmaxf(o0.x, 0.f); o0.y = fmaxf(o0.y, 0.f);
        o0.z = fmaxf(o0.z, 0.f); o0.w = fmaxf(o0.w, 0.f);
        o1.x = fmaxf(o1.x, 0.f); o1.y = fmaxf(o1.y, 0.f);
        o1.z = fmaxf(o1.z, 0.f); o1.w = fmaxf(o1.w, 0.f);
        *(f32x4*)&h1r[(size_t)g * 128 + fb * 16 + c0] = o0;
        *(f32x4*)&h1r[(size_t)g * 128 + fb * 16 + c0 + 4] = o1;
    }
}

// Aggregation layer 2: slots = 4 fb x 2 node-halves (halves 128-aligned).
__global__ __launch_bounds__(256) void aggregate_fb_64(
    const float* __restrict__ h2s, const int* __restrict__ offs,
    const int* __restrict__ pkd, const float* __restrict__ dinv,
    const float* __restrict__ bias, float* __restrict__ h3) {
    __shared__ float acc[128 * 16];
    int slotB = blockIdx.x & 7;
    int fb = slotB & 3;
    int half = slotB >> 2;
    int tile = blockIdx.x >> 3;
    int n0 = half * 25088 + tile * 128;
    if (n0 >= N_NODES) return;
    int tid = threadIdx.x;
#pragma unroll
    for (int i = tid; i < 2048; i += 256) acc[i] = 0.f;
    __syncthreads();

    const f32x4* slab = (const f32x4*)(h2s + (size_t)fb * SLAB);
    int hiCap = half ? N_NODES : 25088;
    int nEnd = min(n0 + 128, hiCap);
    int E0 = offs[n0], E1 = offs[nEnd];
    int EC = E1 - E0;
    int slot = tid >> 2;
    int sub = tid & 3;
    int nit = (EC + 63) >> 6;
    int sBeg = slot * nit;
    int sEnd = min(sBeg + nit, EC);

    f32x4 racc = {0.f, 0.f, 0.f, 0.f};
    int cur = -1;
    for (int eo = sBeg; eo < sEnd; ++eo) {
        int pk = pkd[E0 + eo];
        int s = pk & 0xffff;
        int dl = pk >> 16;
        f32x4 v = slab[(size_t)s * 4 + sub];
        if (dl != cur) {
            if (cur >= 0) {
                atomicAdd(&acc[cur * 16 + sub * 4 + 0], racc.x);
                atomicAdd(&acc[cur * 16 + sub * 4 + 1], racc.y);
                atomicAdd(&acc[cur * 16 + sub * 4 + 2], racc.z);
                atomicAdd(&acc[cur * 16 + sub * 4 + 3], racc.w);
            }
            racc = v;
            cur = dl;
        } else {
            racc += v;
        }
    }
    if (cur >= 0) {
        atomicAdd(&acc[cur * 16 + sub * 4 + 0], racc.x);
        atomicAdd(&acc[cur * 16 + sub * 4 + 1], racc.y);
        atomicAdd(&acc[cur * 16 + sub * 4 + 2], racc.z);
        atomicAdd(&acc[cur * 16 + sub * 4 + 3], racc.w);
    }
    __syncthreads();

    int ln = tid >> 1;
    int g = n0 + ln;
    if (g < nEnd) {
        int c0 = (tid & 1) * 8;
        float di = dinv[g];
        f32x4 a0 = *(f32x4*)&acc[ln * 16 + c0];
        f32x4 a1 = *(f32x4*)&acc[ln * 16 + c0 + 4];
        f32x4 s0 = slab[(size_t)g * 4 + (c0 >> 2)];
        f32x4 s1 = slab[(size_t)g * 4 + (c0 >> 2) + 1];
        const f32x4* bv = (const f32x4*)&bias[fb * 16 + c0];
        f32x4 o0 = di * (a0 + s0) + bv[0];
        f32x4 o1 = di * (a1 + s1) + bv[1];
        *(f32x4*)&h3[(size_t)g * 64 + fb * 16 + c0] = o0;
        *(f32x4*)&h3[(size_t)g * 64 + fb * 16 + c0 + 4] = o1;
    }
}

// Streaming softmax over 64 logits/node: 16 lanes/node, in-register.
__global__ __launch_bounds__(256) void softmax_64(const float* __restrict__ h3,
                                                  float* __restrict__ out) {
    int tid = threadIdx.x;
    int g = blockIdx.x * 16 + (tid >> 4);
    int lane = tid & 15;
    if (g >= N_NODES) return;
    float4 acc = ((const float4*)h3)[(size_t)g * 16 + lane];
    float m = fmaxf(fmaxf(acc.x, acc.y), fmaxf(acc.z, acc.w));
#pragma unroll
    for (int o = 1; o < 16; o <<= 1) m = fmaxf(m, __shfl_xor(m, o, 64));
    float4 e4;
    e4.x = expf(acc.x - m); e4.y = expf(acc.y - m);
    e4.z = expf(acc.z - m); e4.w = expf(acc.w - m);
    float s = e4.x + e4.y + e4.z + e4.w;
#pragma unroll
    for (int o = 1; o < 16; o <<= 1) s += __shfl_xor(s, o, 64);
    float inv = 1.0f / s;
    e4.x *= inv; e4.y *= inv; e4.z *= inv; e4.w *= inv;
    ((float4*)out)[(size_t)g * 16 + lane] = e4;
}

extern "C" void kernel_launch(void* const* d_in, const int* in_sizes, int n_in,
                              void* d_out, int out_size, void* d_ws, size_t ws_size,
                              hipStream_t stream) {
    const float* x  = (const float*)d_in[0];
    const int*   idx = (const int*)d_in[1];
    const float* W1 = (const float*)d_in[2];
    const float* b1 = (const float*)d_in[3];
    const float* W2 = (const float*)d_in[4];
    const float* b2 = (const float*)d_in[5];
    float* outp = (float*)d_out;
    int E = in_sizes[1] / 2;
    int nscan = (N_NODES + 4095) / 4096;  // 13

    char* ws = (char*)d_ws;
    size_t off = 0;
    auto alloc = [&](size_t bytes) {
        size_t o = off;
        off += (bytes + 255) & ~(size_t)255;
        return o;
    };
    // Region A (25.6 MB): h1s slabs; reused after agg1: lower = h2s, upper = h3.
    float* regA = (float*)(ws + alloc((size_t)8 * SLAB * 4));
    float* h1s  = regA;
    float* h2s  = regA;                     // 4 slabs = 12.8 MB
    float* h3   = regA + (size_t)4 * SLAB;  // 12.8 MB
    float* h1r  = (float*)(ws + alloc((size_t)N_NODES * 128 * 4));
    int*   pkd  = (int*)  (ws + alloc((size_t)E * 4));
    int*   cnt  = (int*)  (ws + alloc((size_t)N_NODES * 4));
    int*   offs = (int*)  (ws + alloc((size_t)(N_NODES + 1) * 4));
    int*   cursor = (int*)(ws + alloc((size_t)N_NODES * 4));
    float* dinv = (float*)(ws + alloc((size_t)N_NODES * 4));
    int*   bsum = (int*)  (ws + alloc((size_t)nscan * 4));
    int*   flag = (int*)  (ws + alloc(256));

    hipMemsetAsync(cnt, 0, (size_t)N_NODES * 4, stream);
    detect_idx<<<1, 64, 0, stream>>>(idx, flag);
    count_edges<<<(E + 255) / 256, 256, 0, stream>>>(idx, flag, E, cnt);
    scan_reduce_dinv<<<nscan, 1024, 0, stream>>>(cnt, dinv, bsum, N_NODES);
    scan_partials<<<1, 64, 0, stream>>>(bsum, offs, nscan, N_NODES);
    scan_block<<<nscan, 1024, 0, stream>>>(cnt, bsum, offs, cursor, N_NODES);
    scatter_edges<<<(E + 255) / 256, 256, 0, stream>>>(idx, flag, E, cursor, pkd);
    gemm_128<<<(N_NODES + 63) / 64, 256, 0, stream>>>(x, W1, dinv, h1s, N_NODES);
    aggregate_relu_fb<<<8 * ((N_NODES + 127) / 128), 256, 0, stream>>>(h1s, offs, pkd, dinv, b1, h1r);
    gemm_64<<<(N_NODES + 63) / 64, 256, 0, stream>>>(h1r, W2, dinv, h2s, N_NODES);
    aggregate_fb_64<<<8 * 196, 256, 0, stream>>>(h2s, offs, pkd, dinv, b2, h3);
    softmax_64<<<(N_NODES + 15) / 16, 256, 0, stream>>>(h3, outp);
}